// Round 1
// baseline (5809.440 us; speedup 1.0000x reference)
//
#include <hip/hip_runtime.h>

#define D_DIM 128
#define ROWS 32

// ---------------------------------------------------------------------------
// SpMM: side[dst] += val * x[src]   (edge-parallel, 4 floats per thread)
// ---------------------------------------------------------------------------
__global__ __launch_bounds__(256) void spmm_atomic(
    const float* __restrict__ x, const int* __restrict__ src,
    const int* __restrict__ dst, const float* __restrict__ val,
    float* __restrict__ side, long long total)
{
    long long i = (long long)blockIdx.x * blockDim.x + threadIdx.x;
    if (i >= total) return;
    int e = (int)(i >> 5);   // edge index
    int q = (int)(i & 31);   // which float4 of the 128-dim row
    int s = src[e];
    int d = dst[e];
    float v = val[e];
    const float4 xv = *reinterpret_cast<const float4*>(x + (long long)s * D_DIM + q * 4);
    float* o = side + (long long)d * D_DIM + q * 4;
    // native global_atomic_add_f32 (plain atomicAdd would CAS-loop without
    // -munsafe-fp-atomics)
    unsafeAtomicAdd(o + 0, v * xv.x);
    unsafeAtomicAdd(o + 1, v * xv.y);
    unsafeAtomicAdd(o + 2, v * xv.z);
    unsafeAtomicAdd(o + 3, v * xv.w);
}

// ---------------------------------------------------------------------------
// Fused BiAggregator layer:
//   z = ego + side; m = ego * side
//   s = lrelu(z @ Wsum + bsum); p = lrelu(m @ Wprod + bprod)
//   e = s + p
//   ego_out = e (if non-null);  norm_out = e / max(||e||, 1e-12)
// Block: 256 threads -> 32 rows x 128 cols tile. Thread (rg=tid>>5, cg=tid&31)
// computes rows rg*4..rg*4+3, cols cg*4..cg*4+3 for BOTH gemms (4x4 acc each).
// LDS: z/m tiles (32 KB) + 32-k W chunks (32 KB) = 64 KB -> 2 blocks/CU.
// ---------------------------------------------------------------------------
__global__ __launch_bounds__(256) void fused_layer(
    const float* __restrict__ ego, const float* __restrict__ side,
    const float* __restrict__ Wsum, const float* __restrict__ bsum,
    const float* __restrict__ Wprod, const float* __restrict__ bprod,
    float* __restrict__ ego_out,   // may be nullptr (last layer)
    float* __restrict__ norm_out, int N)
{
    __shared__ float zt[ROWS][D_DIM];
    __shared__ float mt[ROWS][D_DIM];
    __shared__ float wsh[32][D_DIM];
    __shared__ float wph[32][D_DIM];

    const int tid  = threadIdx.x;
    const int row0 = blockIdx.x * ROWS;
    const int cg   = tid & 31;   // col group: cols cg*4 .. cg*4+3
    const int rg   = tid >> 5;   // row group: rows rg*4 .. rg*4+3

    // ---- stage z, m tiles (each thread: 4 float4) ----
    for (int idx = tid; idx < ROWS * 32; idx += 256) {
        int r = idx >> 5, q = idx & 31;
        int row = row0 + r;
        float4 e4 = make_float4(0.f, 0.f, 0.f, 0.f);
        float4 s4 = make_float4(0.f, 0.f, 0.f, 0.f);
        if (row < N) {
            e4 = *reinterpret_cast<const float4*>(ego  + (long long)row * D_DIM + q * 4);
            s4 = *reinterpret_cast<const float4*>(side + (long long)row * D_DIM + q * 4);
        }
        float4 z4 = make_float4(e4.x + s4.x, e4.y + s4.y, e4.z + s4.z, e4.w + s4.w);
        float4 m4 = make_float4(e4.x * s4.x, e4.y * s4.y, e4.z * s4.z, e4.w * s4.w);
        *reinterpret_cast<float4*>(&zt[r][q * 4]) = z4;
        *reinterpret_cast<float4*>(&mt[r][q * 4]) = m4;
    }

    float acc_s[4][4], acc_p[4][4];
#pragma unroll
    for (int a = 0; a < 4; ++a)
#pragma unroll
        for (int b = 0; b < 4; ++b) { acc_s[a][b] = 0.f; acc_p[a][b] = 0.f; }

    // ---- K loop in chunks of 32 ----
    for (int kc = 0; kc < D_DIM; kc += 32) {
        __syncthreads();
        for (int idx = tid; idx < 32 * 32; idx += 256) {
            int kk = idx >> 5, q = idx & 31;
            *reinterpret_cast<float4*>(&wsh[kk][q * 4]) =
                *reinterpret_cast<const float4*>(Wsum + (long long)(kc + kk) * D_DIM + q * 4);
            *reinterpret_cast<float4*>(&wph[kk][q * 4]) =
                *reinterpret_cast<const float4*>(Wprod + (long long)(kc + kk) * D_DIM + q * 4);
        }
        __syncthreads();
#pragma unroll 8
        for (int kk = 0; kk < 32; ++kk) {
            float4 w_s = *reinterpret_cast<const float4*>(&wsh[kk][cg * 4]);
            float4 w_p = *reinterpret_cast<const float4*>(&wph[kk][cg * 4]);
#pragma unroll
            for (int rr = 0; rr < 4; ++rr) {
                float z = zt[rg * 4 + rr][kc + kk];
                float m = mt[rg * 4 + rr][kc + kk];
                acc_s[rr][0] += z * w_s.x;
                acc_s[rr][1] += z * w_s.y;
                acc_s[rr][2] += z * w_s.z;
                acc_s[rr][3] += z * w_s.w;
                acc_p[rr][0] += m * w_p.x;
                acc_p[rr][1] += m * w_p.y;
                acc_p[rr][2] += m * w_p.z;
                acc_p[rr][3] += m * w_p.w;
            }
        }
    }

    // ---- epilogue: bias + leaky relu + add + row L2 norm ----
    const float4 bs = *reinterpret_cast<const float4*>(bsum  + cg * 4);
    const float4 bp = *reinterpret_cast<const float4*>(bprod + cg * 4);
    float ev[4][4];
    float part[4];
#pragma unroll
    for (int rr = 0; rr < 4; ++rr) {
        float bsv[4] = {bs.x, bs.y, bs.z, bs.w};
        float bpv[4] = {bp.x, bp.y, bp.z, bp.w};
        float acc = 0.f;
#pragma unroll
        for (int cc = 0; cc < 4; ++cc) {
            float sv = acc_s[rr][cc] + bsv[cc];
            sv = sv > 0.f ? sv : 0.01f * sv;
            float pv = acc_p[rr][cc] + bpv[cc];
            pv = pv > 0.f ? pv : 0.01f * pv;
            float e = sv + pv;
            ev[rr][cc] = e;
            acc += e * e;
        }
        part[rr] = acc;
    }
    // reduce sum-of-squares across the 32 lanes sharing this row group
#pragma unroll
    for (int off = 1; off < 32; off <<= 1) {
#pragma unroll
        for (int rr = 0; rr < 4; ++rr)
            part[rr] += __shfl_xor(part[rr], off, 32);
    }
#pragma unroll
    for (int rr = 0; rr < 4; ++rr) {
        int row = row0 + rg * 4 + rr;
        if (row >= N) continue;
        float nr  = sqrtf(part[rr]);
        nr        = fmaxf(nr, 1e-12f);
        float inv = 1.0f / nr;
        float4 o  = make_float4(ev[rr][0] * inv, ev[rr][1] * inv,
                                ev[rr][2] * inv, ev[rr][3] * inv);
        *reinterpret_cast<float4*>(norm_out + (long long)row * D_DIM + cg * 4) = o;
        if (ego_out) {
            float4 g = make_float4(ev[rr][0], ev[rr][1], ev[rr][2], ev[rr][3]);
            *reinterpret_cast<float4*>(ego_out + (long long)row * D_DIM + cg * 4) = g;
        }
    }
}

// ---------------------------------------------------------------------------
extern "C" void kernel_launch(void* const* d_in, const int* in_sizes, int n_in,
                              void* d_out, int out_size, void* d_ws, size_t ws_size,
                              hipStream_t stream)
{
    const float* emb   = (const float*)d_in[0];
    const int*   esrc  = (const int*)  d_in[1];
    const int*   edst  = (const int*)  d_in[2];
    const float* evalv = (const float*)d_in[3];
    const float* Wsum  = (const float*)d_in[4];
    const float* bsum  = (const float*)d_in[5];
    const float* Wprod = (const float*)d_in[6];
    const float* bprod = (const float*)d_in[7];
    float* out = (float*)d_out;

    const int D = 128;
    const int N = in_sizes[0] / D;
    const int E = in_sizes[1];
    const int L = in_sizes[5] / D;   // b_sum is (L, D)
    const size_t ND = (size_t)N * D;

    float* side    = (float*)d_ws;       // N*D
    float* ego_buf = side + ND;          // N*D

    // out[0] = embeddings
    hipMemcpyAsync(out, emb, ND * sizeof(float), hipMemcpyDeviceToDevice, stream);

    const float* ego     = emb;
    const float* spmm_in = emb;
    for (int l = 0; l < L; ++l) {
        hipMemsetAsync(side, 0, ND * sizeof(float), stream);

        long long total  = (long long)E * 32;   // E * (D/4)
        long long blocks = (total + 255) / 256;
        spmm_atomic<<<(int)blocks, 256, 0, stream>>>(spmm_in, esrc, edst, evalv,
                                                     side, total);

        float* norm_out = out + (size_t)(l + 1) * ND;
        float* ego_out  = (l + 1 < L) ? ego_buf : nullptr;
        fused_layer<<<(N + ROWS - 1) / ROWS, 256, 0, stream>>>(
            ego, side,
            Wsum + (size_t)l * D * D, bsum + (size_t)l * D,
            Wprod + (size_t)l * D * D, bprod + (size_t)l * D,
            ego_out, norm_out, N);

        ego     = ego_buf;
        spmm_in = norm_out;
    }
}

// Round 2
// 861.347 us; speedup vs baseline: 6.7446x; 6.7446x over previous
//
#include <hip/hip_runtime.h>

#define D_DIM 128
#define ROWS 32

// ---------------------------------------------------------------------------
// Fallback SpMM (atomic): side[dst] += val * x[src]
// ---------------------------------------------------------------------------
__global__ __launch_bounds__(256) void spmm_atomic(
    const float* __restrict__ x, const int* __restrict__ src,
    const int* __restrict__ dst, const float* __restrict__ val,
    float* __restrict__ side, long long total)
{
    long long i = (long long)blockIdx.x * blockDim.x + threadIdx.x;
    if (i >= total) return;
    int e = (int)(i >> 5);
    int q = (int)(i & 31);
    int s = src[e];
    int d = dst[e];
    float v = val[e];
    const float4 xv = *reinterpret_cast<const float4*>(x + (long long)s * D_DIM + q * 4);
    float* o = side + (long long)d * D_DIM + q * 4;
    unsafeAtomicAdd(o + 0, v * xv.x);
    unsafeAtomicAdd(o + 1, v * xv.y);
    unsafeAtomicAdd(o + 2, v * xv.z);
    unsafeAtomicAdd(o + 3, v * xv.w);
}

// ---------------------------------------------------------------------------
// CSR build: histogram -> exclusive scan -> scatter
// ---------------------------------------------------------------------------
__global__ __launch_bounds__(256) void hist_kernel(
    const int* __restrict__ dst, int* __restrict__ cnt, int E)
{
    int i = blockIdx.x * 256 + threadIdx.x;
    if (i < E) atomicAdd(&cnt[dst[i]], 1);
}

// Per-block exclusive scan of cnt -> row_ptr (partial), block totals -> blk_sums
__global__ __launch_bounds__(256) void scan_blocks(
    const int* __restrict__ cnt, int* __restrict__ row_ptr,
    int* __restrict__ blk_sums, int N)
{
    __shared__ int sh[256];
    int i = blockIdx.x * 256 + threadIdx.x;
    int v = (i < N) ? cnt[i] : 0;
    sh[threadIdx.x] = v;
    __syncthreads();
#pragma unroll
    for (int off = 1; off < 256; off <<= 1) {
        int t = (threadIdx.x >= off) ? sh[threadIdx.x - off] : 0;
        __syncthreads();
        sh[threadIdx.x] += t;
        __syncthreads();
    }
    if (i < N) row_ptr[i] = sh[threadIdx.x] - v;   // exclusive
    if (threadIdx.x == 255) blk_sums[blockIdx.x] = sh[255];
}

// Single-block carry scan over blk_sums (in place, exclusive)
__global__ __launch_bounds__(256) void scan_carry(int* __restrict__ blk, int B)
{
    __shared__ int sh[256];
    __shared__ int carry;
    if (threadIdx.x == 0) carry = 0;
    __syncthreads();
    for (int base = 0; base < B; base += 256) {
        int i = base + threadIdx.x;
        int v = (i < B) ? blk[i] : 0;
        sh[threadIdx.x] = v;
        __syncthreads();
#pragma unroll
        for (int off = 1; off < 256; off <<= 1) {
            int t = (threadIdx.x >= off) ? sh[threadIdx.x - off] : 0;
            __syncthreads();
            sh[threadIdx.x] += t;
            __syncthreads();
        }
        int excl = sh[threadIdx.x] - v + carry;
        if (i < B) blk[i] = excl;
        __syncthreads();
        if (threadIdx.x == 255) carry = carry + sh[255];
        __syncthreads();
    }
}

// Add block offsets; produce final row_ptr and a mutable fill cursor copy.
__global__ __launch_bounds__(256) void scan_add(
    int* __restrict__ row_ptr, const int* __restrict__ blk_sums,
    int* __restrict__ row_fill, int N, int E)
{
    int i = blockIdx.x * 256 + threadIdx.x;
    if (i < N) {
        int v = row_ptr[i] + blk_sums[i >> 8];
        row_ptr[i]  = v;
        row_fill[i] = v;
    }
    if (i == 0) row_ptr[N] = E;
}

__global__ __launch_bounds__(256) void scatter_kernel(
    const int* __restrict__ src, const int* __restrict__ dst,
    const float* __restrict__ val, int* __restrict__ row_fill,
    int* __restrict__ csr_src, float* __restrict__ csr_val, int E)
{
    int e = blockIdx.x * 256 + threadIdx.x;
    if (e >= E) return;
    int d = dst[e];
    int pos = atomicAdd(&row_fill[d], 1);
    csr_src[pos] = src[e];
    csr_val[pos] = val[e];
}

// ---------------------------------------------------------------------------
// CSR SpMM: one 32-lane group per dst row; each lane owns 4 of 128 floats.
// Writes each side row exactly once (zero if no edges) -> no memset needed.
// ---------------------------------------------------------------------------
__global__ __launch_bounds__(256) void spmm_csr(
    const float* __restrict__ x, const int* __restrict__ row_ptr,
    const int* __restrict__ csr_src, const float* __restrict__ csr_val,
    float* __restrict__ side, int N)
{
    int row  = blockIdx.x * 8 + (threadIdx.x >> 5);
    int lane = threadIdx.x & 31;
    if (row >= N) return;
    int start = row_ptr[row];
    int end   = row_ptr[row + 1];
    float4 acc = make_float4(0.f, 0.f, 0.f, 0.f);
    for (int j = start; j < end; ++j) {
        int   s = csr_src[j];           // same addr across 32 lanes -> broadcast
        float v = csr_val[j];
        const float4 xv = *reinterpret_cast<const float4*>(
            x + (long long)s * D_DIM + lane * 4);
        acc.x += v * xv.x;
        acc.y += v * xv.y;
        acc.z += v * xv.z;
        acc.w += v * xv.w;
    }
    *reinterpret_cast<float4*>(side + (long long)row * D_DIM + lane * 4) = acc;
}

// ---------------------------------------------------------------------------
// Fused BiAggregator layer (unchanged from R1)
// ---------------------------------------------------------------------------
__global__ __launch_bounds__(256) void fused_layer(
    const float* __restrict__ ego, const float* __restrict__ side,
    const float* __restrict__ Wsum, const float* __restrict__ bsum,
    const float* __restrict__ Wprod, const float* __restrict__ bprod,
    float* __restrict__ ego_out,   // may be nullptr (last layer)
    float* __restrict__ norm_out, int N)
{
    __shared__ float zt[ROWS][D_DIM];
    __shared__ float mt[ROWS][D_DIM];
    __shared__ float wsh[32][D_DIM];
    __shared__ float wph[32][D_DIM];

    const int tid  = threadIdx.x;
    const int row0 = blockIdx.x * ROWS;
    const int cg   = tid & 31;
    const int rg   = tid >> 5;

    for (int idx = tid; idx < ROWS * 32; idx += 256) {
        int r = idx >> 5, q = idx & 31;
        int row = row0 + r;
        float4 e4 = make_float4(0.f, 0.f, 0.f, 0.f);
        float4 s4 = make_float4(0.f, 0.f, 0.f, 0.f);
        if (row < N) {
            e4 = *reinterpret_cast<const float4*>(ego  + (long long)row * D_DIM + q * 4);
            s4 = *reinterpret_cast<const float4*>(side + (long long)row * D_DIM + q * 4);
        }
        float4 z4 = make_float4(e4.x + s4.x, e4.y + s4.y, e4.z + s4.z, e4.w + s4.w);
        float4 m4 = make_float4(e4.x * s4.x, e4.y * s4.y, e4.z * s4.z, e4.w * s4.w);
        *reinterpret_cast<float4*>(&zt[r][q * 4]) = z4;
        *reinterpret_cast<float4*>(&mt[r][q * 4]) = m4;
    }

    float acc_s[4][4], acc_p[4][4];
#pragma unroll
    for (int a = 0; a < 4; ++a)
#pragma unroll
        for (int b = 0; b < 4; ++b) { acc_s[a][b] = 0.f; acc_p[a][b] = 0.f; }

    for (int kc = 0; kc < D_DIM; kc += 32) {
        __syncthreads();
        for (int idx = tid; idx < 32 * 32; idx += 256) {
            int kk = idx >> 5, q = idx & 31;
            *reinterpret_cast<float4*>(&wsh[kk][q * 4]) =
                *reinterpret_cast<const float4*>(Wsum + (long long)(kc + kk) * D_DIM + q * 4);
            *reinterpret_cast<float4*>(&wph[kk][q * 4]) =
                *reinterpret_cast<const float4*>(Wprod + (long long)(kc + kk) * D_DIM + q * 4);
        }
        __syncthreads();
#pragma unroll 8
        for (int kk = 0; kk < 32; ++kk) {
            float4 w_s = *reinterpret_cast<const float4*>(&wsh[kk][cg * 4]);
            float4 w_p = *reinterpret_cast<const float4*>(&wph[kk][cg * 4]);
#pragma unroll
            for (int rr = 0; rr < 4; ++rr) {
                float z = zt[rg * 4 + rr][kc + kk];
                float m = mt[rg * 4 + rr][kc + kk];
                acc_s[rr][0] += z * w_s.x;
                acc_s[rr][1] += z * w_s.y;
                acc_s[rr][2] += z * w_s.z;
                acc_s[rr][3] += z * w_s.w;
                acc_p[rr][0] += m * w_p.x;
                acc_p[rr][1] += m * w_p.y;
                acc_p[rr][2] += m * w_p.z;
                acc_p[rr][3] += m * w_p.w;
            }
        }
    }

    const float4 bs = *reinterpret_cast<const float4*>(bsum  + cg * 4);
    const float4 bp = *reinterpret_cast<const float4*>(bprod + cg * 4);
    float ev[4][4];
    float part[4];
#pragma unroll
    for (int rr = 0; rr < 4; ++rr) {
        float bsv[4] = {bs.x, bs.y, bs.z, bs.w};
        float bpv[4] = {bp.x, bp.y, bp.z, bp.w};
        float acc = 0.f;
#pragma unroll
        for (int cc = 0; cc < 4; ++cc) {
            float sv = acc_s[rr][cc] + bsv[cc];
            sv = sv > 0.f ? sv : 0.01f * sv;
            float pv = acc_p[rr][cc] + bpv[cc];
            pv = pv > 0.f ? pv : 0.01f * pv;
            float e = sv + pv;
            ev[rr][cc] = e;
            acc += e * e;
        }
        part[rr] = acc;
    }
#pragma unroll
    for (int off = 1; off < 32; off <<= 1) {
#pragma unroll
        for (int rr = 0; rr < 4; ++rr)
            part[rr] += __shfl_xor(part[rr], off, 32);
    }
#pragma unroll
    for (int rr = 0; rr < 4; ++rr) {
        int row = row0 + rg * 4 + rr;
        if (row >= N) continue;
        float nr  = sqrtf(part[rr]);
        nr        = fmaxf(nr, 1e-12f);
        float inv = 1.0f / nr;
        float4 o  = make_float4(ev[rr][0] * inv, ev[rr][1] * inv,
                                ev[rr][2] * inv, ev[rr][3] * inv);
        *reinterpret_cast<float4*>(norm_out + (long long)row * D_DIM + cg * 4) = o;
        if (ego_out) {
            float4 g = make_float4(ev[rr][0], ev[rr][1], ev[rr][2], ev[rr][3]);
            *reinterpret_cast<float4*>(ego_out + (long long)row * D_DIM + cg * 4) = g;
        }
    }
}

// ---------------------------------------------------------------------------
extern "C" void kernel_launch(void* const* d_in, const int* in_sizes, int n_in,
                              void* d_out, int out_size, void* d_ws, size_t ws_size,
                              hipStream_t stream)
{
    const float* emb   = (const float*)d_in[0];
    const int*   esrc  = (const int*)  d_in[1];
    const int*   edst  = (const int*)  d_in[2];
    const float* evalv = (const float*)d_in[3];
    const float* Wsum  = (const float*)d_in[4];
    const float* bsum  = (const float*)d_in[5];
    const float* Wprod = (const float*)d_in[6];
    const float* bprod = (const float*)d_in[7];
    float* out = (float*)d_out;

    const int D = 128;
    const int N = in_sizes[0] / D;
    const int E = in_sizes[1];
    const int L = in_sizes[5] / D;
    const size_t ND = (size_t)N * D;
    const int B = (N + 255) / 256;           // scan blocks

    // workspace layout
    char* ws = (char*)d_ws;
    float* side    = (float*)ws;                 ws += ND * sizeof(float);
    float* ego_buf = (float*)ws;                 ws += ND * sizeof(float);
    size_t base_bytes = (size_t)(ws - (char*)d_ws);
    int*   row_ptr  = (int*)ws;                  ws += (size_t)(N + 1) * sizeof(int);
    int*   row_fill = (int*)ws;                  ws += (size_t)N * sizeof(int);
    int*   blk_sums = (int*)ws;                  ws += (size_t)B * sizeof(int);
    int*   csr_src  = (int*)ws;                  ws += (size_t)E * sizeof(int);
    float* csr_val  = (float*)ws;                ws += (size_t)E * sizeof(float);
    size_t csr_bytes = (size_t)(ws - (char*)d_ws);
    const bool use_csr = (ws_size >= csr_bytes);
    (void)base_bytes;

    // out[0] = embeddings
    hipMemcpyAsync(out, emb, ND * sizeof(float), hipMemcpyDeviceToDevice, stream);

    if (use_csr) {
        // ---- build CSR once; reused for both layers ----
        hipMemsetAsync(row_fill, 0, (size_t)N * sizeof(int), stream);   // as histogram
        hist_kernel<<<(E + 255) / 256, 256, 0, stream>>>(edst, row_fill, E);
        scan_blocks<<<B, 256, 0, stream>>>(row_fill, row_ptr, blk_sums, N);
        scan_carry<<<1, 256, 0, stream>>>(blk_sums, B);
        scan_add<<<B, 256, 0, stream>>>(row_ptr, blk_sums, row_fill, N, E);
        scatter_kernel<<<(E + 255) / 256, 256, 0, stream>>>(
            esrc, edst, evalv, row_fill, csr_src, csr_val, E);
    }

    const float* ego     = emb;
    const float* spmm_in = emb;
    for (int l = 0; l < L; ++l) {
        if (use_csr) {
            spmm_csr<<<(N + 7) / 8, 256, 0, stream>>>(
                spmm_in, row_ptr, csr_src, csr_val, side, N);
        } else {
            hipMemsetAsync(side, 0, ND * sizeof(float), stream);
            long long total  = (long long)E * 32;
            long long blocks = (total + 255) / 256;
            spmm_atomic<<<(int)blocks, 256, 0, stream>>>(spmm_in, esrc, edst, evalv,
                                                         side, total);
        }

        float* norm_out = out + (size_t)(l + 1) * ND;
        float* ego_out  = (l + 1 < L) ? ego_buf : nullptr;
        fused_layer<<<(N + ROWS - 1) / ROWS, 256, 0, stream>>>(
            ego, side,
            Wsum + (size_t)l * D * D, bsum + (size_t)l * D,
            Wprod + (size_t)l * D * D, bprod + (size_t)l * D,
            ego_out, norm_out, N);

        ego     = ego_buf;
        spmm_in = norm_out;
    }
}

// Round 3
// 773.240 us; speedup vs baseline: 7.5131x; 1.1139x over previous
//
#include <hip/hip_runtime.h>

#define D_DIM 128
#define ROWS 32        // fp32 fallback tile
#define MROWS 64       // mfma kernel rows per block
#define ZPAD 136       // bf16 elems per LDS row: 272 B = 16B-aligned, low bank conflict

typedef __bf16 bf16x8 __attribute__((ext_vector_type(8)));
typedef __bf16 bf16x4 __attribute__((ext_vector_type(4)));
typedef float  f32x4  __attribute__((ext_vector_type(4)));

// ---------------------------------------------------------------------------
// Fallback SpMM (atomic): side[dst] += val * x[src]
// ---------------------------------------------------------------------------
__global__ __launch_bounds__(256) void spmm_atomic(
    const float* __restrict__ x, const int* __restrict__ src,
    const int* __restrict__ dst, const float* __restrict__ val,
    float* __restrict__ side, long long total)
{
    long long i = (long long)blockIdx.x * blockDim.x + threadIdx.x;
    if (i >= total) return;
    int e = (int)(i >> 5);
    int q = (int)(i & 31);
    int s = src[e];
    int d = dst[e];
    float v = val[e];
    const float4 xv = *reinterpret_cast<const float4*>(x + (long long)s * D_DIM + q * 4);
    float* o = side + (long long)d * D_DIM + q * 4;
    unsafeAtomicAdd(o + 0, v * xv.x);
    unsafeAtomicAdd(o + 1, v * xv.y);
    unsafeAtomicAdd(o + 2, v * xv.z);
    unsafeAtomicAdd(o + 3, v * xv.w);
}

// ---------------------------------------------------------------------------
// CSR build: histogram -> exclusive scan -> scatter
// ---------------------------------------------------------------------------
__global__ __launch_bounds__(256) void hist_kernel(
    const int* __restrict__ dst, int* __restrict__ cnt, int E)
{
    int i = blockIdx.x * 256 + threadIdx.x;
    if (i < E) atomicAdd(&cnt[dst[i]], 1);
}

__global__ __launch_bounds__(256) void scan_blocks(
    const int* __restrict__ cnt, int* __restrict__ row_ptr,
    int* __restrict__ blk_sums, int N)
{
    __shared__ int sh[256];
    int i = blockIdx.x * 256 + threadIdx.x;
    int v = (i < N) ? cnt[i] : 0;
    sh[threadIdx.x] = v;
    __syncthreads();
#pragma unroll
    for (int off = 1; off < 256; off <<= 1) {
        int t = (threadIdx.x >= off) ? sh[threadIdx.x - off] : 0;
        __syncthreads();
        sh[threadIdx.x] += t;
        __syncthreads();
    }
    if (i < N) row_ptr[i] = sh[threadIdx.x] - v;
    if (threadIdx.x == 255) blk_sums[blockIdx.x] = sh[255];
}

__global__ __launch_bounds__(256) void scan_carry(int* __restrict__ blk, int B)
{
    __shared__ int sh[256];
    __shared__ int carry;
    if (threadIdx.x == 0) carry = 0;
    __syncthreads();
    for (int base = 0; base < B; base += 256) {
        int i = base + threadIdx.x;
        int v = (i < B) ? blk[i] : 0;
        sh[threadIdx.x] = v;
        __syncthreads();
#pragma unroll
        for (int off = 1; off < 256; off <<= 1) {
            int t = (threadIdx.x >= off) ? sh[threadIdx.x - off] : 0;
            __syncthreads();
            sh[threadIdx.x] += t;
            __syncthreads();
        }
        int excl = sh[threadIdx.x] - v + carry;
        if (i < B) blk[i] = excl;
        __syncthreads();
        if (threadIdx.x == 255) carry = carry + sh[255];
        __syncthreads();
    }
}

__global__ __launch_bounds__(256) void scan_add(
    int* __restrict__ row_ptr, const int* __restrict__ blk_sums,
    int* __restrict__ row_fill, int N, int E)
{
    int i = blockIdx.x * 256 + threadIdx.x;
    if (i < N) {
        int v = row_ptr[i] + blk_sums[i >> 8];
        row_ptr[i]  = v;
        row_fill[i] = v;
    }
    if (i == 0) row_ptr[N] = E;
}

__global__ __launch_bounds__(256) void scatter_kernel(
    const int* __restrict__ src, const int* __restrict__ dst,
    const float* __restrict__ val, int* __restrict__ row_fill,
    int* __restrict__ csr_src, float* __restrict__ csr_val, int E)
{
    int e = blockIdx.x * 256 + threadIdx.x;
    if (e >= E) return;
    int d = dst[e];
    int pos = atomicAdd(&row_fill[d], 1);
    csr_src[pos] = src[e];
    csr_val[pos] = val[e];
}

// ---------------------------------------------------------------------------
// W^T bf16 precompute: WT[l][n][k] = bf16(W[l][k][n]), both matrices.
// ---------------------------------------------------------------------------
__global__ __launch_bounds__(256) void wt_convert(
    const float* __restrict__ Wsum, const float* __restrict__ Wprod,
    __bf16* __restrict__ WTsum, __bf16* __restrict__ WTprod, int total)
{
    int i = blockIdx.x * 256 + threadIdx.x;
    if (i >= total) return;
    int l  = i >> 14;
    int nk = i & 16383;
    int n  = nk >> 7;
    int k  = nk & 127;
    int widx = (l << 14) + (k << 7) + n;
    WTsum[i]  = (__bf16)Wsum[widx];
    WTprod[i] = (__bf16)Wprod[widx];
}

// ---------------------------------------------------------------------------
// CSR SpMM: one 32-lane group per dst row; 4-way unrolled gather (MLP).
// ---------------------------------------------------------------------------
__global__ __launch_bounds__(256) void spmm_csr(
    const float* __restrict__ x, const int* __restrict__ row_ptr,
    const int* __restrict__ csr_src, const float* __restrict__ csr_val,
    float* __restrict__ side, int N)
{
    int row  = blockIdx.x * 8 + (threadIdx.x >> 5);
    int lane = threadIdx.x & 31;
    if (row >= N) return;
    int start = row_ptr[row];
    int end   = row_ptr[row + 1];
    float4 acc = make_float4(0.f, 0.f, 0.f, 0.f);
    int j = start;
    for (; j + 4 <= end; j += 4) {
        int   s0 = csr_src[j + 0], s1 = csr_src[j + 1];
        int   s2 = csr_src[j + 2], s3 = csr_src[j + 3];
        float v0 = csr_val[j + 0], v1 = csr_val[j + 1];
        float v2 = csr_val[j + 2], v3 = csr_val[j + 3];
        const float4 x0 = *reinterpret_cast<const float4*>(x + (long long)s0 * D_DIM + lane * 4);
        const float4 x1 = *reinterpret_cast<const float4*>(x + (long long)s1 * D_DIM + lane * 4);
        const float4 x2 = *reinterpret_cast<const float4*>(x + (long long)s2 * D_DIM + lane * 4);
        const float4 x3 = *reinterpret_cast<const float4*>(x + (long long)s3 * D_DIM + lane * 4);
        acc.x += v0 * x0.x + v1 * x1.x + v2 * x2.x + v3 * x3.x;
        acc.y += v0 * x0.y + v1 * x1.y + v2 * x2.y + v3 * x3.y;
        acc.z += v0 * x0.z + v1 * x1.z + v2 * x2.z + v3 * x3.z;
        acc.w += v0 * x0.w + v1 * x1.w + v2 * x2.w + v3 * x3.w;
    }
    for (; j < end; ++j) {
        int   s = csr_src[j];
        float v = csr_val[j];
        const float4 xv = *reinterpret_cast<const float4*>(x + (long long)s * D_DIM + lane * 4);
        acc.x += v * xv.x;
        acc.y += v * xv.y;
        acc.z += v * xv.z;
        acc.w += v * xv.w;
    }
    *reinterpret_cast<float4*>(side + (long long)row * D_DIM + lane * 4) = acc;
}

// ---------------------------------------------------------------------------
// MFMA fused BiAggregator layer.
//   Block: 256 thr = 4 waves; 64 rows x 128 cols. Wave w: rows w*16..w*16+15.
//   z=ego+side, m=ego*side staged as bf16 in LDS (full K=128, one barrier).
//   B-frags read from pre-transposed bf16 WT (global, L2-resident).
//   mfma_f32_16x16x32_bf16: A[m=lane&15][k=quad*8+j]; D: col=lane&15,
//   row=quad*4+reg (m89/m120-verified layouts).
// ---------------------------------------------------------------------------
__global__ __launch_bounds__(256) void fused_layer_mfma(
    const float* __restrict__ ego, const float* __restrict__ side,
    const __bf16* __restrict__ WTsum, const float* __restrict__ bsum,
    const __bf16* __restrict__ WTprod, const float* __restrict__ bprod,
    float* __restrict__ ego_out,   // may be nullptr (last layer)
    float* __restrict__ norm_out, int N)
{
    __shared__ __bf16 zt[MROWS][ZPAD];
    __shared__ __bf16 mt[MROWS][ZPAD];

    const int tid  = threadIdx.x;
    const int row0 = blockIdx.x * MROWS;

    // ---- stage z, m as bf16 (each thread 8 float4-pairs) ----
    for (int idx = tid; idx < MROWS * 32; idx += 256) {
        int r = idx >> 5, q = idx & 31;
        int row = row0 + r;
        float4 e4 = make_float4(0.f, 0.f, 0.f, 0.f);
        float4 s4 = make_float4(0.f, 0.f, 0.f, 0.f);
        if (row < N) {
            e4 = *reinterpret_cast<const float4*>(ego  + (long long)row * D_DIM + q * 4);
            s4 = *reinterpret_cast<const float4*>(side + (long long)row * D_DIM + q * 4);
        }
        bf16x4 z4, m4;
        z4[0] = (__bf16)(e4.x + s4.x); z4[1] = (__bf16)(e4.y + s4.y);
        z4[2] = (__bf16)(e4.z + s4.z); z4[3] = (__bf16)(e4.w + s4.w);
        m4[0] = (__bf16)(e4.x * s4.x); m4[1] = (__bf16)(e4.y * s4.y);
        m4[2] = (__bf16)(e4.z * s4.z); m4[3] = (__bf16)(e4.w * s4.w);
        *reinterpret_cast<bf16x4*>(&zt[r][q * 4]) = z4;
        *reinterpret_cast<bf16x4*>(&mt[r][q * 4]) = m4;
    }
    __syncthreads();

    const int wave = tid >> 6;
    const int lane = tid & 63;
    const int ln   = lane & 15;        // n within tile / m within A
    const int quad = lane >> 4;        // k-block selector (A/B), row-block (C)
    const int mloc = wave * 16;        // this wave's row base within block

    f32x4 acc_s[8], acc_p[8];
#pragma unroll
    for (int nt = 0; nt < 8; ++nt) {
        acc_s[nt] = (f32x4){0.f, 0.f, 0.f, 0.f};
        acc_p[nt] = (f32x4){0.f, 0.f, 0.f, 0.f};
    }

#pragma unroll
    for (int ks = 0; ks < 4; ++ks) {
        const int k0 = ks * 32 + quad * 8;
        bf16x8 az = *reinterpret_cast<const bf16x8*>(&zt[mloc + ln][k0]);
        bf16x8 am = *reinterpret_cast<const bf16x8*>(&mt[mloc + ln][k0]);
#pragma unroll
        for (int nt = 0; nt < 8; ++nt) {
            const long long wofs = (long long)(nt * 16 + ln) * D_DIM + k0;
            bf16x8 bs = *reinterpret_cast<const bf16x8*>(WTsum  + wofs);
            bf16x8 bp = *reinterpret_cast<const bf16x8*>(WTprod + wofs);
            acc_s[nt] = __builtin_amdgcn_mfma_f32_16x16x32_bf16(az, bs, acc_s[nt], 0, 0, 0);
            acc_p[nt] = __builtin_amdgcn_mfma_f32_16x16x32_bf16(am, bp, acc_p[nt], 0, 0, 0);
        }
    }

    // ---- epilogue: bias + lrelu + add, row L2-norm, stores ----
    float bsv[8], bpv[8];
#pragma unroll
    for (int nt = 0; nt < 8; ++nt) {
        bsv[nt] = bsum[nt * 16 + ln];
        bpv[nt] = bprod[nt * 16 + ln];
    }
    float part[4] = {0.f, 0.f, 0.f, 0.f};
#pragma unroll
    for (int nt = 0; nt < 8; ++nt) {
#pragma unroll
        for (int r = 0; r < 4; ++r) {
            float sv = acc_s[nt][r] + bsv[nt];
            sv = sv > 0.f ? sv : 0.01f * sv;
            float pv = acc_p[nt][r] + bpv[nt];
            pv = pv > 0.f ? pv : 0.01f * pv;
            float e = sv + pv;
            acc_s[nt][r] = e;           // reuse as e-store
            part[r] += e * e;
        }
    }
#pragma unroll
    for (int off = 1; off < 16; off <<= 1) {
#pragma unroll
        for (int r = 0; r < 4; ++r)
            part[r] += __shfl_xor(part[r], off, 16);
    }
#pragma unroll
    for (int r = 0; r < 4; ++r) {
        int row = row0 + mloc + quad * 4 + r;
        if (row >= N) continue;
        float inv = 1.0f / fmaxf(sqrtf(part[r]), 1e-12f);
        long long base = (long long)row * D_DIM + ln;
#pragma unroll
        for (int nt = 0; nt < 8; ++nt)
            norm_out[base + nt * 16] = acc_s[nt][r] * inv;
        if (ego_out) {
#pragma unroll
            for (int nt = 0; nt < 8; ++nt)
                ego_out[base + nt * 16] = acc_s[nt][r];
        }
    }
}

// ---------------------------------------------------------------------------
// fp32 fallback fused layer (R1 version)
// ---------------------------------------------------------------------------
__global__ __launch_bounds__(256) void fused_layer_f32(
    const float* __restrict__ ego, const float* __restrict__ side,
    const float* __restrict__ Wsum, const float* __restrict__ bsum,
    const float* __restrict__ Wprod, const float* __restrict__ bprod,
    float* __restrict__ ego_out, float* __restrict__ norm_out, int N)
{
    __shared__ float zt[ROWS][D_DIM];
    __shared__ float mt[ROWS][D_DIM];
    __shared__ float wsh[32][D_DIM];
    __shared__ float wph[32][D_DIM];

    const int tid  = threadIdx.x;
    const int row0 = blockIdx.x * ROWS;
    const int cg   = tid & 31;
    const int rg   = tid >> 5;

    for (int idx = tid; idx < ROWS * 32; idx += 256) {
        int r = idx >> 5, q = idx & 31;
        int row = row0 + r;
        float4 e4 = make_float4(0.f, 0.f, 0.f, 0.f);
        float4 s4 = make_float4(0.f, 0.f, 0.f, 0.f);
        if (row < N) {
            e4 = *reinterpret_cast<const float4*>(ego  + (long long)row * D_DIM + q * 4);
            s4 = *reinterpret_cast<const float4*>(side + (long long)row * D_DIM + q * 4);
        }
        float4 z4 = make_float4(e4.x + s4.x, e4.y + s4.y, e4.z + s4.z, e4.w + s4.w);
        float4 m4 = make_float4(e4.x * s4.x, e4.y * s4.y, e4.z * s4.z, e4.w * s4.w);
        *reinterpret_cast<float4*>(&zt[r][q * 4]) = z4;
        *reinterpret_cast<float4*>(&mt[r][q * 4]) = m4;
    }

    float acc_s[4][4], acc_p[4][4];
#pragma unroll
    for (int a = 0; a < 4; ++a)
#pragma unroll
        for (int b = 0; b < 4; ++b) { acc_s[a][b] = 0.f; acc_p[a][b] = 0.f; }

    for (int kc = 0; kc < D_DIM; kc += 32) {
        __syncthreads();
        for (int idx = tid; idx < 32 * 32; idx += 256) {
            int kk = idx >> 5, q = idx & 31;
            *reinterpret_cast<float4*>(&wsh[kk][q * 4]) =
                *reinterpret_cast<const float4*>(Wsum + (long long)(kc + kk) * D_DIM + q * 4);
            *reinterpret_cast<float4*>(&wph[kk][q * 4]) =
                *reinterpret_cast<const float4*>(Wprod + (long long)(kc + kk) * D_DIM + q * 4);
        }
        __syncthreads();
#pragma unroll 8
        for (int kk = 0; kk < 32; ++kk) {
            float4 w_s = *reinterpret_cast<const float4*>(&wsh[kk][cg * 4]);
            float4 w_p = *reinterpret_cast<const float4*>(&wph[kk][cg * 4]);
#pragma unroll
            for (int rr = 0; rr < 4; ++rr) {
                float z = zt[rg * 4 + rr][kc + kk];
                float m = mt[rg * 4 + rr][kc + kk];
                acc_s[rr][0] += z * w_s.x; acc_s[rr][1] += z * w_s.y;
                acc_s[rr][2] += z * w_s.z; acc_s[rr][3] += z * w_s.w;
                acc_p[rr][0] += m * w_p.x; acc_p[rr][1] += m * w_p.y;
                acc_p[rr][2] += m * w_p.z; acc_p[rr][3] += m * w_p.w;
            }
        }
    }

    const float4 bs = *reinterpret_cast<const float4*>(bsum  + cg * 4);
    const float4 bp = *reinterpret_cast<const float4*>(bprod + cg * 4);
    float ev[4][4];
    float part[4];
#pragma unroll
    for (int rr = 0; rr < 4; ++rr) {
        float bsv[4] = {bs.x, bs.y, bs.z, bs.w};
        float bpv[4] = {bp.x, bp.y, bp.z, bp.w};
        float acc = 0.f;
#pragma unroll
        for (int cc = 0; cc < 4; ++cc) {
            float sv = acc_s[rr][cc] + bsv[cc];
            sv = sv > 0.f ? sv : 0.01f * sv;
            float pv = acc_p[rr][cc] + bpv[cc];
            pv = pv > 0.f ? pv : 0.01f * pv;
            float e = sv + pv;
            ev[rr][cc] = e;
            acc += e * e;
        }
        part[rr] = acc;
    }
#pragma unroll
    for (int off = 1; off < 32; off <<= 1) {
#pragma unroll
        for (int rr = 0; rr < 4; ++rr)
            part[rr] += __shfl_xor(part[rr], off, 32);
    }
#pragma unroll
    for (int rr = 0; rr < 4; ++rr) {
        int row = row0 + rg * 4 + rr;
        if (row >= N) continue;
        float inv = 1.0f / fmaxf(sqrtf(part[rr]), 1e-12f);
        float4 o  = make_float4(ev[rr][0] * inv, ev[rr][1] * inv,
                                ev[rr][2] * inv, ev[rr][3] * inv);
        *reinterpret_cast<float4*>(norm_out + (long long)row * D_DIM + cg * 4) = o;
        if (ego_out) {
            float4 g = make_float4(ev[rr][0], ev[rr][1], ev[rr][2], ev[rr][3]);
            *reinterpret_cast<float4*>(ego_out + (long long)row * D_DIM + cg * 4) = g;
        }
    }
}

// ---------------------------------------------------------------------------
extern "C" void kernel_launch(void* const* d_in, const int* in_sizes, int n_in,
                              void* d_out, int out_size, void* d_ws, size_t ws_size,
                              hipStream_t stream)
{
    const float* emb   = (const float*)d_in[0];
    const int*   esrc  = (const int*)  d_in[1];
    const int*   edst  = (const int*)  d_in[2];
    const float* evalv = (const float*)d_in[3];
    const float* Wsum  = (const float*)d_in[4];
    const float* bsum  = (const float*)d_in[5];
    const float* Wprod = (const float*)d_in[6];
    const float* bprod = (const float*)d_in[7];
    float* out = (float*)d_out;

    const int D = 128;
    const int N = in_sizes[0] / D;
    const int E = in_sizes[1];
    const int L = in_sizes[5] / D;
    const size_t ND = (size_t)N * D;
    const int B = (N + 255) / 256;

    // workspace layout
    char* ws = (char*)d_ws;
    float* side    = (float*)ws;                 ws += ND * sizeof(float);
    float* ego_buf = (float*)ws;                 ws += ND * sizeof(float);
    int*   row_ptr  = (int*)ws;                  ws += (size_t)(N + 1) * sizeof(int);
    int*   row_fill = (int*)ws;                  ws += (size_t)N * sizeof(int);
    int*   blk_sums = (int*)ws;                  ws += (size_t)B * sizeof(int);
    int*   csr_src  = (int*)ws;                  ws += (size_t)E * sizeof(int);
    float* csr_val  = (float*)ws;                ws += (size_t)E * sizeof(float);
    size_t csr_bytes = (size_t)(ws - (char*)d_ws);
    __bf16* WTsum  = (__bf16*)ws;                ws += (size_t)L * D * D * sizeof(__bf16);
    __bf16* WTprod = (__bf16*)ws;                ws += (size_t)L * D * D * sizeof(__bf16);
    size_t mfma_bytes = (size_t)(ws - (char*)d_ws);

    const bool use_csr  = (ws_size >= csr_bytes);
    const bool use_mfma = (ws_size >= mfma_bytes);

    // out[0] = embeddings
    hipMemcpyAsync(out, emb, ND * sizeof(float), hipMemcpyDeviceToDevice, stream);

    if (use_csr) {
        hipMemsetAsync(row_fill, 0, (size_t)N * sizeof(int), stream);
        hist_kernel<<<(E + 255) / 256, 256, 0, stream>>>(edst, row_fill, E);
        scan_blocks<<<B, 256, 0, stream>>>(row_fill, row_ptr, blk_sums, N);
        scan_carry<<<1, 256, 0, stream>>>(blk_sums, B);
        scan_add<<<B, 256, 0, stream>>>(row_ptr, blk_sums, row_fill, N, E);
        scatter_kernel<<<(E + 255) / 256, 256, 0, stream>>>(
            esrc, edst, evalv, row_fill, csr_src, csr_val, E);
    }
    if (use_mfma) {
        int total = L * D * D;
        wt_convert<<<(total + 255) / 256, 256, 0, stream>>>(
            Wsum, Wprod, WTsum, WTprod, total);
    }

    const float* ego     = emb;
    const float* spmm_in = emb;
    for (int l = 0; l < L; ++l) {
        if (use_csr) {
            spmm_csr<<<(N + 7) / 8, 256, 0, stream>>>(
                spmm_in, row_ptr, csr_src, csr_val, side, N);
        } else {
            hipMemsetAsync(side, 0, ND * sizeof(float), stream);
            long long total  = (long long)E * 32;
            long long blocks = (total + 255) / 256;
            spmm_atomic<<<(int)blocks, 256, 0, stream>>>(spmm_in, esrc, edst, evalv,
                                                         side, total);
        }

        float* norm_out = out + (size_t)(l + 1) * ND;
        float* ego_out  = (l + 1 < L) ? ego_buf : nullptr;
        if (use_mfma) {
            fused_layer_mfma<<<(N + MROWS - 1) / MROWS, 256, 0, stream>>>(
                ego, side,
                WTsum + (size_t)l * D * D, bsum + (size_t)l * D,
                WTprod + (size_t)l * D * D, bprod + (size_t)l * D,
                ego_out, norm_out, N);
        } else {
            fused_layer_f32<<<(N + ROWS - 1) / ROWS, 256, 0, stream>>>(
                ego, side,
                Wsum + (size_t)l * D * D, bsum + (size_t)l * D,
                Wprod + (size_t)l * D * D, bprod + (size_t)l * D,
                ego_out, norm_out, N);
        }

        ego     = ego_buf;
        spmm_in = norm_out;
    }
}